// Round 17
// baseline (5530.658 us; speedup 1.0000x reference)
//
#include <hip/hip_runtime.h>
#include <math.h>

#define NN 512
#define BB 32
#define TT 12
#define HH 12
#define UU 64
#define CAP 128
#define RTOT (NN * BB)          // 16384 rows

__device__ __forceinline__ float sigm(float x) { return 1.f / (1.f + expf(-x)); }

__global__ void zero_kernel(float* __restrict__ p, int n) {
    int i = blockIdx.x * 256 + threadIdx.x;
    if (i < n) p[i] = 0.0f;
}

// ---------------- ELL pass 1: quad-bucketed compaction (wave per row) -----------
// ell8 quad: q8(j) = (2j + ((j>>2)&1)) & 7   (offset j*32 + ((j>>2)&1)*16)
// ell4 quad: q4(j) = j & 7                   (offset j*16)
// tmp layout: [(row*8+q)*32 + k], bucket counts bc[row*8+q].
__global__ __launch_bounds__(256) void ell_pass1(const float* __restrict__ sup,
                                                 int2* __restrict__ tmp8,
                                                 int2* __restrict__ tmp4,
                                                 int* __restrict__ bc8,
                                                 int* __restrict__ bc4,
                                                 int* __restrict__ ecnt) {
    int wave = (blockIdx.x * 256 + threadIdx.x) >> 6;
    int lane = threadIdx.x & 63;
    if (wave >= 2 * NN) return;
    const float* row = sup + (size_t)wave * NN;
    int base8[8], base4[8];
    #pragma unroll
    for (int q = 0; q < 8; ++q) { base8[q] = 0; base4[q] = 0; }
    int total = 0;
    for (int k = 0; k < 8; ++k) {
        int j = k * 64 + lane;
        float v = row[j];
        bool nz = (v != 0.0f);
        int q8 = (2 * j + ((j >> 2) & 1)) & 7;
        int q4 = j & 7;
        unsigned long long below = (1ull << lane) - 1ull;
        #pragma unroll
        for (int q = 0; q < 8; ++q) {
            unsigned long long m8 = __ballot(nz && q8 == q);
            unsigned long long m4 = __ballot(nz && q4 == q);
            if (nz && q8 == q) {
                int pos = base8[q] + __popcll(m8 & below);
                if (pos < 32)
                    tmp8[((size_t)wave * 8 + q) * 32 + pos] =
                        make_int2(j * 32 + ((j >> 2) & 1) * 16, __float_as_int(v));
            }
            if (nz && q4 == q) {
                int pos = base4[q] + __popcll(m4 & below);
                if (pos < 32)
                    tmp4[((size_t)wave * 8 + q) * 32 + pos] =
                        make_int2(j * 16, __float_as_int(v));
            }
            base8[q] += __popcll(m8);
            base4[q] += __popcll(m4);
        }
        total += __popcll(__ballot(nz));
    }
    if (lane == 0) {
        ecnt[wave] = total < CAP ? total : CAP;
        #pragma unroll
        for (int q = 0; q < 8; ++q) {
            bc8[wave * 8 + q] = base8[q] < 32 ? base8[q] : 32;
            bc4[wave * 8 + q] = base4[q] < 32 ? base4[q] : 32;
        }
    }
}

// ---------------- ELL scheduler: greedy per-trip quad balancing -----------------
// One lane per (table, 64-row wave-group). Per trip, each row (in order) takes its
// remaining entry in the least-loaded quad -> at any trip the wave's 64 lanes
// spread ~8 per quad (b128 ideal). Emits trip bytes only (no data movement).
__global__ __launch_bounds__(32) void ell_sched(const int* __restrict__ bc8,
                                                const int* __restrict__ bc4,
                                                unsigned char* __restrict__ sched8,
                                                unsigned char* __restrict__ sched4) {
    __shared__ unsigned char rem[32][64][8];
    __shared__ unsigned char rowrem[32][64];
    int t = threadIdx.x;
    int tbl = t >> 4;            // 0: ell8, 1: ell4
    int grp = t & 15;            // 16 groups x 64 rows
    const int* bc = tbl ? bc4 : bc8;
    unsigned char* sched = tbl ? sched4 : sched8;
    int totrem = 0;
    for (int r = 0; r < 64; ++r) {
        int rr = 0;
        #pragma unroll
        for (int q = 0; q < 8; ++q) {
            int c = bc[(grp * 64 + r) * 8 + q];
            rem[t][r][q] = (unsigned char)c;
            rr += c;
        }
        rowrem[t][r] = (unsigned char)rr;
        totrem += rr;
    }
    for (int p = 0; totrem > 0 && p < CAP; ++p) {
        int l0 = 0, l1 = 0, l2 = 0, l3 = 0, l4 = 0, l5 = 0, l6 = 0, l7 = 0;
        for (int r = 0; r < 64; ++r) {
            if (rowrem[t][r] == 0) continue;
            int bq = -1, bl = 1 << 20;
            {
                int rm, ld;
                rm = rem[t][r][0]; ld = l0; if (rm > 0 && ld < bl) { bl = ld; bq = 0; }
                rm = rem[t][r][1]; ld = l1; if (rm > 0 && ld < bl) { bl = ld; bq = 1; }
                rm = rem[t][r][2]; ld = l2; if (rm > 0 && ld < bl) { bl = ld; bq = 2; }
                rm = rem[t][r][3]; ld = l3; if (rm > 0 && ld < bl) { bl = ld; bq = 3; }
                rm = rem[t][r][4]; ld = l4; if (rm > 0 && ld < bl) { bl = ld; bq = 4; }
                rm = rem[t][r][5]; ld = l5; if (rm > 0 && ld < bl) { bl = ld; bq = 5; }
                rm = rem[t][r][6]; ld = l6; if (rm > 0 && ld < bl) { bl = ld; bq = 6; }
                rm = rem[t][r][7]; ld = l7; if (rm > 0 && ld < bl) { bl = ld; bq = 7; }
            }
            int k = (int)rem[t][r][bq] - 1;      // take from bucket end
            rem[t][r][bq] = (unsigned char)k;
            rowrem[t][r]--;
            totrem--;
            l0 += (bq == 0); l1 += (bq == 1); l2 += (bq == 2); l3 += (bq == 3);
            l4 += (bq == 4); l5 += (bq == 5); l6 += (bq == 6); l7 += (bq == 7);
            sched[((size_t)(grp * 64 + r) * 8 + bq) * 32 + k] = (unsigned char)p;
        }
    }
}

// ---------------- ELL scatter: place entries at scheduled trips -----------------
__global__ __launch_bounds__(256) void ell_scatter(const int2* __restrict__ tmp8,
                                                   const int2* __restrict__ tmp4,
                                                   const int* __restrict__ bc8,
                                                   const int* __restrict__ bc4,
                                                   const unsigned char* __restrict__ sched8,
                                                   const unsigned char* __restrict__ sched4,
                                                   int2* __restrict__ ell8,
                                                   int2* __restrict__ ell4) {
    int wave = (blockIdx.x * 256 + threadIdx.x) >> 6;
    int lane = threadIdx.x & 63;
    if (wave >= 2 * NN) return;
    #pragma unroll
    for (int i = 0; i < 4; ++i) {
        int flat = i * 64 + lane;
        int q = flat >> 5, k = flat & 31;
        if (k < bc8[wave * 8 + q]) {
            int p = sched8[((size_t)wave * 8 + q) * 32 + k];
            ell8[(size_t)p * 1024 + wave] = tmp8[((size_t)wave * 8 + q) * 32 + k];
        }
        if (k < bc4[wave * 8 + q]) {
            int p = sched4[((size_t)wave * 8 + q) * 32 + k];
            ell4[(size_t)p * 1024 + wave] = tmp4[((size_t)wave * 8 + q) * 32 + k];
        }
    }
}

// per-64-row-group max counts: wmax[s*8+g] = max ecnt over rows [g*64, g*64+64)
__global__ void wmax_kernel(const int* __restrict__ ecnt, int* __restrict__ wmax) {
    int g = threadIdx.x;
    if (g >= 16) return;
    int s = g >> 3, grp = g & 7;
    int m = 0;
    for (int i = 0; i < 64; ++i) {
        int c = ecnt[s * NN + grp * 64 + i];
        m = c > m ? c : m;
    }
    wmax[g] = m;
}

// ---------------- weight prep: permute to [oq][m][c][WD] + x-row table ----------
// Wmod semantics: m=0 slot holds W0-W2-W4 (Chebyshev pre-subtraction).
__global__ void wprep(const float* __restrict__ src, float* __restrict__ dstP,
                      float* __restrict__ dstX, int C, int OO, int WD, int L0) {
    int idx = blockIdx.x * 256 + threadIdx.x;
    int total = 5 * C * OO;
    if (idx >= total) return;
    int oi = idx % WD;
    int rem = idx / WD;
    int c = rem % C;
    int rem2 = rem / C;
    int m = rem2 % 5;
    int oq = rem2 / 5;
    int o = oq * WD + oi;
    int crow = L0 ? (c + 1) : c;
    size_t base = (size_t)crow * 5 * OO + o;
    float v;
    if (m == 0) v = src[base] - src[base + 2 * OO] - src[base + 4 * OO];
    else        v = src[base + (size_t)m * OO];
    dstP[idx] = v;
    if (L0 && c == 0) {
        size_t b0 = (size_t)o;       // crow = 0
        float xvv;
        if (m == 0) xvv = src[b0] - src[b0 + 2 * OO] - src[b0 + 4 * OO];
        else        xvv = src[b0 + (size_t)m * OO];
        dstX[(oq * 5 + m) * WD + oi] = xvv;
    }
}

// ---------------- fused gconv: GEMM-in-registers + Chebyshev combine ------------
// Phase 1: acc[m][oi] = bias-init + sum_c A[c][n]*Wp[oq][m][c][oi]; W wave-uniform
// global (scalar cache). Phase 2: 2 LDS tiles, 4 gathers (pre-baked offsets,
// wave-uniform padded trip counts); out = Z024 + S1(Z1+2S1Z2) + S2(Z3+2S2Z4).
// GATE (WD=8): r-half -> g[u<64]=sigm(.)*h (rh-fusion); u-half -> g[u>=64]=sigm(.)
// CAND (WD=4): h_new = u*h_old + (1-u)*tanh(.); A loads rh directly from g.
template<bool L0, bool GATE>
__global__ __launch_bounds__(512) void fused(const float* __restrict__ hA,
                                             const float* __restrict__ hB,
                                             const float* __restrict__ g,
                                             const float* __restrict__ Wp,
                                             const float* __restrict__ Xr,
                                             const float* __restrict__ xv,
                                             const float* __restrict__ bias,
                                             const int2* __restrict__ ell,
                                             const int* __restrict__ wmax,
                                             float* __restrict__ gout,
                                             const float* __restrict__ hOld,
                                             float* __restrict__ hNew) {
    constexpr int C  = L0 ? 64 : 128;
    constexpr int WD = GATE ? 8 : 4;

    __shared__ float S[512 * WD * 2];
    float* T0 = S;
    float* T1 = S + 512 * WD;

    int bid = blockIdx.x;
    int swz = (bid & 7) * 64 + (bid >> 3);  // XCD-contiguous (512 blocks, %8==0)
    int b = swz >> 4, oq = swz & 15;
    int o0 = oq * WD;
    int n = threadIdx.x;
    int wm0 = wmax[n >> 6];                 // wave-uniform trip counts
    int wm1 = wmax[8 + (n >> 6)];
    float xn = L0 ? xv[b * 512 + n] : 0.f;

    // ---- phase 1: GEMM in registers; W via uniform global reads ----
    const float* Wb = Wp + (size_t)oq * 5 * C * WD;
    float acc[5][WD];
    #pragma unroll
    for (int oi = 0; oi < WD; ++oi) acc[0][oi] = bias[o0 + oi];   // bias-init
    #pragma unroll
    for (int m = 1; m < 5; ++m)
        #pragma unroll
        for (int oi = 0; oi < WD; ++oi) acc[m][oi] = 0.f;

    #pragma unroll 2
    for (int c = 0; c < C; ++c) {
        float a;
        if (L0) {
            if (GATE) a = hA[(size_t)((b << 6) + c) * 512 + n];
            else      a = g[(size_t)((b << 7) + c) * 512 + n];          // rh
        } else {
            if (c < 64) {
                a = hA[(size_t)((b << 6) + c) * 512 + n];
            } else {
                int u = c - 64;
                if (GATE) a = hB[(size_t)((b << 6) + u) * 512 + n];
                else      a = g[(size_t)((b << 7) + u) * 512 + n];      // rh
            }
        }
        #pragma unroll
        for (int m = 0; m < 5; ++m) {
            const float* wrow = Wb + ((size_t)m * C + c) * WD;
            #pragma unroll
            for (int oi = 0; oi < WD; ++oi)
                acc[m][oi] += a * wrow[oi];
        }
    }

    // rank-1 x-term (L0) from x-row table
    if (L0) {
        const float* xr = Xr + (size_t)oq * 5 * WD;
        #pragma unroll
        for (int m = 0; m < 5; ++m)
            #pragma unroll
            for (int oi = 0; oi < WD; ++oi)
                acc[m][oi] += xn * xr[m * WD + oi];
    }

    float uval[WD], hval[WD];
    if (!GATE) {
        #pragma unroll
        for (int oi = 0; oi < WD; ++oi) {
            uval[oi] = g[(size_t)((b << 7) + 64 + o0 + oi) * 512 + n];
            hval[oi] = hOld[(size_t)((b << 6) + o0 + oi) * 512 + n];
        }
    }

    // ---- stage Z2 -> T0, Z4 -> T1 (half-select by bit 2: matches ell8) ----
    int hsel = (n >> 2) & 1;
    if constexpr (WD == 8) {
        *(float4*)&T0[n * 8 + hsel * 4] =
            make_float4(acc[2][0], acc[2][1], acc[2][2], acc[2][3]);
        *(float4*)&T0[n * 8 + (hsel ^ 1) * 4] =
            make_float4(acc[2][4], acc[2][5], acc[2][6], acc[2][7]);
        *(float4*)&T1[n * 8 + hsel * 4] =
            make_float4(acc[4][0], acc[4][1], acc[4][2], acc[4][3]);
        *(float4*)&T1[n * 8 + (hsel ^ 1) * 4] =
            make_float4(acc[4][4], acc[4][5], acc[4][6], acc[4][7]);
    } else {
        *(float4*)&T0[n * 4] = make_float4(acc[2][0], acc[2][1], acc[2][2], acc[2][3]);
        *(float4*)&T1[n * 4] = make_float4(acc[4][0], acc[4][1], acc[4][2], acc[4][3]);
    }

    auto gather = [&](const float* T, const int2* e0, int wm, float* o) {
        const char* Tbyte = (const char*)T;
        float a0[WD];
        #pragma unroll
        for (int i = 0; i < WD; ++i) a0[i] = 0.f;
        #pragma unroll 2
        for (int p = 0; p < wm; ++p) {              // uniform, padded with zeros
            int2 e = e0[(size_t)p << 10];
            float v = __int_as_float(e.y);
            if constexpr (WD == 8) {
                float4 x0 = *(const float4*)(Tbyte + e.x);
                float4 x1 = *(const float4*)(Tbyte + (e.x ^ 16));
                a0[0] += v * x0.x; a0[1] += v * x0.y; a0[2] += v * x0.z; a0[3] += v * x0.w;
                a0[4] += v * x1.x; a0[5] += v * x1.y; a0[6] += v * x1.z; a0[7] += v * x1.w;
            } else {
                float4 x0 = *(const float4*)(Tbyte + e.x);
                a0[0] += v * x0.x; a0[1] += v * x0.y; a0[2] += v * x0.z; a0[3] += v * x0.w;
            }
        }
        #pragma unroll
        for (int i = 0; i < WD; ++i) o[i] = a0[i];
    };
    auto put = [&](float* T, const float* y) {
        if constexpr (WD == 8) {
            *(float4*)&T[n * 8 + hsel * 4]       = make_float4(y[0], y[1], y[2], y[3]);
            *(float4*)&T[n * 8 + (hsel ^ 1) * 4] = make_float4(y[4], y[5], y[6], y[7]);
        } else {
            *(float4*)&T[n * 4] = make_float4(y[0], y[1], y[2], y[3]);
        }
    };

    const int2* e00 = ell + n;          // support 0 row base
    const int2* e01 = ell + NN + n;     // support 1 row base
    float g2[WD], g4[WD], t1[WD];

    __syncthreads();                    // bar 1: T0/T1 staged

    gather(T0, e00, wm0, t1);           // S1 Z2
    #pragma unroll
    for (int oi = 0; oi < WD; ++oi) acc[1][oi] += 2.f * t1[oi];   // y1 = Z1+2 S1 Z2
    gather(T1, e01, wm1, t1);           // S2 Z4
    #pragma unroll
    for (int oi = 0; oi < WD; ++oi) acc[3][oi] += 2.f * t1[oi];   // y2 = Z3+2 S2 Z4

    __syncthreads();                    // bar 2: hop-1 reads done

    put(T0, acc[1]);
    put(T1, acc[3]);

    __syncthreads();                    // bar 3: y tiles ready

    gather(T0, e00, wm0, g2);           // S1 y1
    gather(T1, e01, wm1, g4);           // S2 y2

    #pragma unroll
    for (int oi = 0; oi < WD; ++oi) {
        float accf = acc[0][oi] + g2[oi] + g4[oi];
        if (GATE) {
            float s = sigm(accf);
            if (oq < 8) {               // r-half: write rh = r * h (rh-fusion)
                const float* hG = L0 ? hA : hB;
                float hv = hG[(size_t)((b << 6) + o0 + oi) * 512 + n];
                gout[(size_t)((b << 7) + o0 + oi) * 512 + n] = s * hv;
            } else {
                gout[(size_t)((b << 7) + o0 + oi) * 512 + n] = s;
            }
        } else {
            float cv = tanhf(accf);
            hNew[(size_t)((b << 6) + o0 + oi) * 512 + n] =
                uval[oi] * hval[oi] + (1.f - uval[oi]) * cv;
        }
    }
}

// ---------------- projection ----------------------------------------------------
__global__ void proj_kernel(const float* __restrict__ h1, const float* __restrict__ pW,
                            const float* __restrict__ pb, float* __restrict__ outt) {
    int r = blockIdx.x * 256 + threadIdx.x;
    if (r >= RTOT) return;
    int b = r >> 9, n = r & 511;
    float acc = pb[0];
    #pragma unroll 16
    for (int u = 0; u < 64; ++u)
        acc += h1[(size_t)((b << 6) + u) * 512 + n] * pW[u];
    outt[b * NN + n] = acc;
}

// ================================================================================
extern "C" void kernel_launch(void* const* d_in, const int* in_sizes, int n_in,
                              void* d_out, int out_size, void* d_ws, size_t ws_size,
                              hipStream_t stream) {
    const float* inputs   = (const float*)d_in[0];
    const float* supports = (const float*)d_in[1];
    const float* enc0_Wg = (const float*)d_in[2];
    const float* enc0_bg = (const float*)d_in[3];
    const float* enc0_Wc = (const float*)d_in[4];
    const float* enc0_bc = (const float*)d_in[5];
    const float* enc1_Wg = (const float*)d_in[6];
    const float* enc1_bg = (const float*)d_in[7];
    const float* enc1_Wc = (const float*)d_in[8];
    const float* enc1_bc = (const float*)d_in[9];
    const float* dec0_Wg = (const float*)d_in[10];
    const float* dec0_bg = (const float*)d_in[11];
    const float* dec0_Wc = (const float*)d_in[12];
    const float* dec0_bc = (const float*)d_in[13];
    const float* dec1_Wg = (const float*)d_in[14];
    const float* dec1_bg = (const float*)d_in[15];
    const float* dec1_Wc = (const float*)d_in[16];
    const float* dec1_bc = (const float*)d_in[17];
    const float* projW   = (const float*)d_in[18];
    const float* projb   = (const float*)d_in[19];
    float* out = (float*)d_out;

    char* wsb = (char*)d_ws;
    size_t off = 0;
    auto alloc = [&](size_t bytes) -> char* {
        char* p = wsb + off;
        off = (off + bytes + 255) & ~(size_t)255;
        return p;
    };
    int2*  ell8  = (int2*)alloc((size_t)CAP * 1024 * 8);
    int2*  ell4  = (int2*)alloc((size_t)CAP * 1024 * 8);
    int2*  tmp8  = (int2*)alloc((size_t)1024 * 8 * 32 * 8);
    int2*  tmp4  = (int2*)alloc((size_t)1024 * 8 * 32 * 8);
    int*   bc8   = (int*)alloc((size_t)1024 * 8 * 4);
    int*   bc4   = (int*)alloc((size_t)1024 * 8 * 4);
    unsigned char* sched8 = (unsigned char*)alloc((size_t)1024 * 8 * 32);
    unsigned char* sched4 = (unsigned char*)alloc((size_t)1024 * 8 * 32);
    int*   ecnt  = (int*)alloc((size_t)2 * NN * 4);
    int*   wmax  = (int*)alloc((size_t)16 * 4);
    float* h0a   = (float*)alloc((size_t)RTOT * UU * 4);     // [b][u][n]
    float* h1a   = (float*)alloc((size_t)RTOT * UU * 4);
    float* xzero = (float*)alloc((size_t)RTOT * 4);
    float* h0b   = (float*)alloc((size_t)RTOT * UU * 4);
    float* h1b   = (float*)alloc((size_t)RTOT * UU * 4);
    float* g     = (float*)alloc((size_t)RTOT * 128 * 4);    // [b][u][n]: u<64 rh, u>=64 ugate
    float* p_e0g = (float*)alloc((size_t)5 * 64 * 128 * 4);
    float* x_e0g = (float*)alloc((size_t)16 * 5 * 8 * 4);
    float* p_e0c = (float*)alloc((size_t)5 * 64 * 64 * 4);
    float* x_e0c = (float*)alloc((size_t)16 * 5 * 4 * 4);
    float* p_e1g = (float*)alloc((size_t)5 * 128 * 128 * 4);
    float* p_e1c = (float*)alloc((size_t)5 * 128 * 64 * 4);
    float* p_d0g = (float*)alloc((size_t)5 * 64 * 128 * 4);
    float* x_d0g = (float*)alloc((size_t)16 * 5 * 8 * 4);
    float* p_d0c = (float*)alloc((size_t)5 * 64 * 64 * 4);
    float* x_d0c = (float*)alloc((size_t)16 * 5 * 4 * 4);
    float* p_d1g = (float*)alloc((size_t)5 * 128 * 128 * 4);
    float* p_d1c = (float*)alloc((size_t)5 * 128 * 64 * 4);
    float* xdum  = (float*)alloc((size_t)16 * 5 * 8 * 4);
    if (off > ws_size) return;

    // zero-fill ELL buffers (padding entries = {off 0, val 0}) BEFORE build
    {
        int nz = CAP * 1024 * 4;  // ell8 + ell4 as ints (contiguous)
        zero_kernel<<<(nz + 255) / 256, 256, 0, stream>>>((float*)ell8, nz);
    }
    ell_pass1<<<256, 256, 0, stream>>>(supports, tmp8, tmp4, bc8, bc4, ecnt);
    ell_sched<<<1, 32, 0, stream>>>(bc8, bc4, sched8, sched4);
    ell_scatter<<<256, 256, 0, stream>>>(tmp8, tmp4, bc8, bc4, sched8, sched4, ell8, ell4);
    wmax_kernel<<<1, 16, 0, stream>>>(ecnt, wmax);
    {
        int nz = RTOT * UU * 2 + RTOT;  // h0a, h1a, xzero contiguous
        zero_kernel<<<(nz + 255) / 256, 256, 0, stream>>>(h0a, nz);
    }
    wprep<<<(5 * 64 * 128 + 255) / 256, 256, 0, stream>>>(enc0_Wg, p_e0g, x_e0g, 64, 128, 8, 1);
    wprep<<<(5 * 64 * 64 + 255) / 256, 256, 0, stream>>>(enc0_Wc, p_e0c, x_e0c, 64, 64, 4, 1);
    wprep<<<(5 * 128 * 128 + 255) / 256, 256, 0, stream>>>(enc1_Wg, p_e1g, xdum, 128, 128, 8, 0);
    wprep<<<(5 * 128 * 64 + 255) / 256, 256, 0, stream>>>(enc1_Wc, p_e1c, xdum, 128, 64, 4, 0);
    wprep<<<(5 * 64 * 128 + 255) / 256, 256, 0, stream>>>(dec0_Wg, p_d0g, x_d0g, 64, 128, 8, 1);
    wprep<<<(5 * 64 * 64 + 255) / 256, 256, 0, stream>>>(dec0_Wc, p_d0c, x_d0c, 64, 64, 4, 1);
    wprep<<<(5 * 128 * 128 + 255) / 256, 256, 0, stream>>>(dec1_Wg, p_d1g, xdum, 128, 128, 8, 0);
    wprep<<<(5 * 128 * 64 + 255) / 256, 256, 0, stream>>>(dec1_Wc, p_d1c, xdum, 128, 64, 4, 0);

    float *h0c = h0a, *h0n = h0b, *h1c = h1a, *h1n = h1b;

    auto cell_l0 = [&](const float* x_bn, const float* Wg_, const float* Xg_,
                       const float* bg_, const float* Wc_, const float* Xc_,
                       const float* bc_) {
        fused<true, true><<<512, 512, 0, stream>>>(h0c, nullptr, g, Wg_, Xg_, x_bn,
                                                   bg_, ell8, wmax, g, nullptr, nullptr);
        fused<true, false><<<512, 512, 0, stream>>>(h0c, nullptr, g, Wc_, Xc_, x_bn,
                                                    bc_, ell4, wmax, nullptr, h0c, h0n);
        float* t = h0c; h0c = h0n; h0n = t;
    };
    auto cell_l1 = [&](const float* Wg_, const float* bg_,
                       const float* Wc_, const float* bc_) {
        fused<false, true><<<512, 512, 0, stream>>>(h0c, h1c, g, Wg_, nullptr, nullptr,
                                                    bg_, ell8, wmax, g, nullptr, nullptr);
        fused<false, false><<<512, 512, 0, stream>>>(h0c, h1c, g, Wc_, nullptr, nullptr,
                                                     bc_, ell4, wmax, nullptr, h1c, h1n);
        float* t = h1c; h1c = h1n; h1n = t;
    };

    for (int t = 0; t < TT; ++t) {
        cell_l0(inputs + (size_t)t * BB * NN, p_e0g, x_e0g, enc0_bg, p_e0c, x_e0c, enc0_bc);
        cell_l1(p_e1g, enc1_bg, p_e1c, enc1_bc);
    }
    for (int t = 0; t < HH; ++t) {
        const float* xin = (t == 0) ? xzero : (out + (size_t)(t - 1) * BB * NN);
        cell_l0(xin, p_d0g, x_d0g, dec0_bg, p_d0c, x_d0c, dec0_bc);
        cell_l1(p_d1g, dec1_bg, p_d1c, dec1_bc);
        proj_kernel<<<(RTOT + 255) / 256, 256, 0, stream>>>(h1c, projW, projb,
                                                            out + (size_t)t * BB * NN);
    }
}

// Round 18
// 4768.895 us; speedup vs baseline: 1.1597x; 1.1597x over previous
//
#include <hip/hip_runtime.h>
#include <math.h>

#define NN 512
#define BB 32
#define TT 12
#define HH 12
#define UU 64
#define CAP 128
#define RTOT (NN * BB)          // 16384 rows

__device__ __forceinline__ float sigm(float x) { return 1.f / (1.f + expf(-x)); }

// ---------------- ELL build with pre-baked LDS byte offsets ---------------------
// ell8: {j*32 + ((j>>2)&1)*16, val}  (WD=8 tiles; other half = off ^ 16)
// ell4: {j*16, val}                  (WD=4 tiles)
// Buffers pre-zeroed; entries beyond a row's count stay {0, 0.0f} (padding reads
// are wave-broadcast of offset 0 -> free).
__global__ __launch_bounds__(256) void build_ell(const float* __restrict__ sup,
                                                 int2* __restrict__ ell8,
                                                 int2* __restrict__ ell4,
                                                 int* __restrict__ ecnt) {
    int wave = (blockIdx.x * blockDim.x + threadIdx.x) >> 6;
    int lane = threadIdx.x & 63;
    if (wave >= 2 * NN) return;
    const float* row = sup + (size_t)wave * NN;
    int base = 0;
    for (int k = 0; k < NN / 64; ++k) {
        float v = row[k * 64 + lane];
        unsigned long long m = __ballot(v != 0.0f);
        int pre = __popcll(m & ((1ull << lane) - 1ull));
        if (v != 0.0f) {
            int pos = base + pre;
            if (pos < CAP) {
                int j = k * 64 + lane;
                int vb = __float_as_int(v);
                ell8[(size_t)pos * 1024 + wave] = make_int2(j * 32 + ((j >> 2) & 1) * 16, vb);
                ell4[(size_t)pos * 1024 + wave] = make_int2(j * 16, vb);
            }
        }
        base += __popcll(m);
    }
    if (lane == 0) ecnt[wave] = base < CAP ? base : CAP;
}

__global__ void zero_kernel(float* __restrict__ p, int n) {
    int i = blockIdx.x * 256 + threadIdx.x;
    if (i < n) p[i] = 0.0f;
}

// per-64-row-group max counts: wmax[s*8+g] = max ecnt over rows [g*64, g*64+64)
__global__ void wmax_kernel(const int* __restrict__ ecnt, int* __restrict__ wmax) {
    int g = threadIdx.x;
    if (g >= 16) return;
    int s = g >> 3, grp = g & 7;
    int m = 0;
    for (int i = 0; i < 64; ++i) {
        int c = ecnt[s * NN + grp * 64 + i];
        m = c > m ? c : m;
    }
    wmax[g] = m;
}

// ---------------- weight prep: permute to [oq][m][c][WD] + x-row table ----------
// Wmod semantics: m=0 slot holds W0-W2-W4 (Chebyshev pre-subtraction).
__global__ void wprep(const float* __restrict__ src, float* __restrict__ dstP,
                      float* __restrict__ dstX, int C, int OO, int WD, int L0) {
    int idx = blockIdx.x * 256 + threadIdx.x;
    int total = 5 * C * OO;
    if (idx >= total) return;
    int oi = idx % WD;
    int rem = idx / WD;
    int c = rem % C;
    int rem2 = rem / C;
    int m = rem2 % 5;
    int oq = rem2 / 5;
    int o = oq * WD + oi;
    int crow = L0 ? (c + 1) : c;
    size_t base = (size_t)crow * 5 * OO + o;
    float v;
    if (m == 0) v = src[base] - src[base + 2 * OO] - src[base + 4 * OO];
    else        v = src[base + (size_t)m * OO];
    dstP[idx] = v;
    if (L0 && c == 0) {
        size_t b0 = (size_t)o;       // crow = 0
        float xvv;
        if (m == 0) xvv = src[b0] - src[b0 + 2 * OO] - src[b0 + 4 * OO];
        else        xvv = src[b0 + (size_t)m * OO];
        dstX[(oq * 5 + m) * WD + oi] = xvv;
    }
}

// ---------------- fused gconv: GEMM-in-registers + Chebyshev combine ------------
// Phase 1: acc[m][oi] = bias-init + sum_c A[c][n]*Wp[oq][m][c][oi]; W wave-uniform
// global (scalar cache). Phase 2: 2 LDS tiles, 4 gathers (pre-baked offsets,
// wave-uniform padded trip counts); out = Z024 + S1(Z1+2S1Z2) + S2(Z3+2S2Z4).
// GATE (WD=8): r-half -> g[u<64]=sigm(.)*h (rh-fusion); u-half -> g[u>=64]=sigm(.)
// CAND (WD=4): h_new = u*h_old + (1-u)*tanh(.); A loads rh directly from g.
template<bool L0, bool GATE>
__global__ __launch_bounds__(512) void fused(const float* __restrict__ hA,
                                             const float* __restrict__ hB,
                                             const float* __restrict__ g,
                                             const float* __restrict__ Wp,
                                             const float* __restrict__ Xr,
                                             const float* __restrict__ xv,
                                             const float* __restrict__ bias,
                                             const int2* __restrict__ ell,
                                             const int* __restrict__ wmax,
                                             float* __restrict__ gout,
                                             const float* __restrict__ hOld,
                                             float* __restrict__ hNew) {
    constexpr int C  = L0 ? 64 : 128;
    constexpr int WD = GATE ? 8 : 4;

    __shared__ float S[512 * WD * 2];
    float* T0 = S;
    float* T1 = S + 512 * WD;

    int bid = blockIdx.x;
    int swz = (bid & 7) * 64 + (bid >> 3);  // XCD-contiguous (512 blocks, %8==0)
    int b = swz >> 4, oq = swz & 15;
    int o0 = oq * WD;
    int n = threadIdx.x;
    int wm0 = wmax[n >> 6];                 // wave-uniform trip counts
    int wm1 = wmax[8 + (n >> 6)];
    float xn = L0 ? xv[b * 512 + n] : 0.f;

    // ---- phase 1: GEMM in registers; W via uniform global reads ----
    const float* Wb = Wp + (size_t)oq * 5 * C * WD;
    float acc[5][WD];
    #pragma unroll
    for (int oi = 0; oi < WD; ++oi) acc[0][oi] = bias[o0 + oi];   // bias-init
    #pragma unroll
    for (int m = 1; m < 5; ++m)
        #pragma unroll
        for (int oi = 0; oi < WD; ++oi) acc[m][oi] = 0.f;

    #pragma unroll 2
    for (int c = 0; c < C; ++c) {
        float a;
        if (L0) {
            if (GATE) a = hA[(size_t)((b << 6) + c) * 512 + n];
            else      a = g[(size_t)((b << 7) + c) * 512 + n];          // rh
        } else {
            if (c < 64) {
                a = hA[(size_t)((b << 6) + c) * 512 + n];
            } else {
                int u = c - 64;
                if (GATE) a = hB[(size_t)((b << 6) + u) * 512 + n];
                else      a = g[(size_t)((b << 7) + u) * 512 + n];      // rh
            }
        }
        #pragma unroll
        for (int m = 0; m < 5; ++m) {
            const float* wrow = Wb + ((size_t)m * C + c) * WD;
            #pragma unroll
            for (int oi = 0; oi < WD; ++oi)
                acc[m][oi] += a * wrow[oi];
        }
    }

    // rank-1 x-term (L0) from x-row table
    if (L0) {
        const float* xr = Xr + (size_t)oq * 5 * WD;
        #pragma unroll
        for (int m = 0; m < 5; ++m)
            #pragma unroll
            for (int oi = 0; oi < WD; ++oi)
                acc[m][oi] += xn * xr[m * WD + oi];
    }

    float uval[WD], hval[WD];
    if (!GATE) {
        #pragma unroll
        for (int oi = 0; oi < WD; ++oi) {
            uval[oi] = g[(size_t)((b << 7) + 64 + o0 + oi) * 512 + n];
            hval[oi] = hOld[(size_t)((b << 6) + o0 + oi) * 512 + n];
        }
    }

    // ---- stage Z2 -> T0, Z4 -> T1 (half-select by bit 2: matches ell8) ----
    int hsel = (n >> 2) & 1;
    if constexpr (WD == 8) {
        *(float4*)&T0[n * 8 + hsel * 4] =
            make_float4(acc[2][0], acc[2][1], acc[2][2], acc[2][3]);
        *(float4*)&T0[n * 8 + (hsel ^ 1) * 4] =
            make_float4(acc[2][4], acc[2][5], acc[2][6], acc[2][7]);
        *(float4*)&T1[n * 8 + hsel * 4] =
            make_float4(acc[4][0], acc[4][1], acc[4][2], acc[4][3]);
        *(float4*)&T1[n * 8 + (hsel ^ 1) * 4] =
            make_float4(acc[4][4], acc[4][5], acc[4][6], acc[4][7]);
    } else {
        *(float4*)&T0[n * 4] = make_float4(acc[2][0], acc[2][1], acc[2][2], acc[2][3]);
        *(float4*)&T1[n * 4] = make_float4(acc[4][0], acc[4][1], acc[4][2], acc[4][3]);
    }

    auto gather = [&](const float* T, const int2* e0, int wm, float* o) {
        const char* Tbyte = (const char*)T;
        float a0[WD];
        #pragma unroll
        for (int i = 0; i < WD; ++i) a0[i] = 0.f;
        #pragma unroll 2
        for (int p = 0; p < wm; ++p) {              // uniform, padded with zeros
            int2 e = e0[(size_t)p << 10];
            float v = __int_as_float(e.y);
            if constexpr (WD == 8) {
                float4 x0 = *(const float4*)(Tbyte + e.x);
                float4 x1 = *(const float4*)(Tbyte + (e.x ^ 16));
                a0[0] += v * x0.x; a0[1] += v * x0.y; a0[2] += v * x0.z; a0[3] += v * x0.w;
                a0[4] += v * x1.x; a0[5] += v * x1.y; a0[6] += v * x1.z; a0[7] += v * x1.w;
            } else {
                float4 x0 = *(const float4*)(Tbyte + e.x);
                a0[0] += v * x0.x; a0[1] += v * x0.y; a0[2] += v * x0.z; a0[3] += v * x0.w;
            }
        }
        #pragma unroll
        for (int i = 0; i < WD; ++i) o[i] = a0[i];
    };
    auto put = [&](float* T, const float* y) {
        if constexpr (WD == 8) {
            *(float4*)&T[n * 8 + hsel * 4]       = make_float4(y[0], y[1], y[2], y[3]);
            *(float4*)&T[n * 8 + (hsel ^ 1) * 4] = make_float4(y[4], y[5], y[6], y[7]);
        } else {
            *(float4*)&T[n * 4] = make_float4(y[0], y[1], y[2], y[3]);
        }
    };

    const int2* e00 = ell + n;          // support 0 row base
    const int2* e01 = ell + NN + n;     // support 1 row base
    float g2[WD], g4[WD], t1[WD];

    __syncthreads();                    // bar 1: T0/T1 staged

    gather(T0, e00, wm0, t1);           // S1 Z2
    #pragma unroll
    for (int oi = 0; oi < WD; ++oi) acc[1][oi] += 2.f * t1[oi];   // y1 = Z1+2 S1 Z2
    gather(T1, e01, wm1, t1);           // S2 Z4
    #pragma unroll
    for (int oi = 0; oi < WD; ++oi) acc[3][oi] += 2.f * t1[oi];   // y2 = Z3+2 S2 Z4

    __syncthreads();                    // bar 2: hop-1 reads done

    put(T0, acc[1]);
    put(T1, acc[3]);

    __syncthreads();                    // bar 3: y tiles ready

    gather(T0, e00, wm0, g2);           // S1 y1
    gather(T1, e01, wm1, g4);           // S2 y2

    #pragma unroll
    for (int oi = 0; oi < WD; ++oi) {
        float accf = acc[0][oi] + g2[oi] + g4[oi];
        if (GATE) {
            float s = sigm(accf);
            if (oq < 8) {               // r-half: write rh = r * h (rh-fusion)
                const float* hG = L0 ? hA : hB;
                float hv = hG[(size_t)((b << 6) + o0 + oi) * 512 + n];
                gout[(size_t)((b << 7) + o0 + oi) * 512 + n] = s * hv;
            } else {
                gout[(size_t)((b << 7) + o0 + oi) * 512 + n] = s;
            }
        } else {
            float cv = tanhf(accf);
            hNew[(size_t)((b << 6) + o0 + oi) * 512 + n] =
                uval[oi] * hval[oi] + (1.f - uval[oi]) * cv;
        }
    }
}

// ---------------- projection ----------------------------------------------------
__global__ void proj_kernel(const float* __restrict__ h1, const float* __restrict__ pW,
                            const float* __restrict__ pb, float* __restrict__ outt) {
    int r = blockIdx.x * 256 + threadIdx.x;
    if (r >= RTOT) return;
    int b = r >> 9, n = r & 511;
    float acc = pb[0];
    #pragma unroll 16
    for (int u = 0; u < 64; ++u)
        acc += h1[(size_t)((b << 6) + u) * 512 + n] * pW[u];
    outt[b * NN + n] = acc;
}

// ================================================================================
extern "C" void kernel_launch(void* const* d_in, const int* in_sizes, int n_in,
                              void* d_out, int out_size, void* d_ws, size_t ws_size,
                              hipStream_t stream) {
    const float* inputs   = (const float*)d_in[0];
    const float* supports = (const float*)d_in[1];
    const float* enc0_Wg = (const float*)d_in[2];
    const float* enc0_bg = (const float*)d_in[3];
    const float* enc0_Wc = (const float*)d_in[4];
    const float* enc0_bc = (const float*)d_in[5];
    const float* enc1_Wg = (const float*)d_in[6];
    const float* enc1_bg = (const float*)d_in[7];
    const float* enc1_Wc = (const float*)d_in[8];
    const float* enc1_bc = (const float*)d_in[9];
    const float* dec0_Wg = (const float*)d_in[10];
    const float* dec0_bg = (const float*)d_in[11];
    const float* dec0_Wc = (const float*)d_in[12];
    const float* dec0_bc = (const float*)d_in[13];
    const float* dec1_Wg = (const float*)d_in[14];
    const float* dec1_bg = (const float*)d_in[15];
    const float* dec1_Wc = (const float*)d_in[16];
    const float* dec1_bc = (const float*)d_in[17];
    const float* projW   = (const float*)d_in[18];
    const float* projb   = (const float*)d_in[19];
    float* out = (float*)d_out;

    char* wsb = (char*)d_ws;
    size_t off = 0;
    auto alloc = [&](size_t bytes) -> char* {
        char* p = wsb + off;
        off = (off + bytes + 255) & ~(size_t)255;
        return p;
    };
    int2*  ell8  = (int2*)alloc((size_t)CAP * 1024 * 8);
    int2*  ell4  = (int2*)alloc((size_t)CAP * 1024 * 8);
    int*   ecnt  = (int*)alloc((size_t)2 * NN * 4);
    int*   wmax  = (int*)alloc((size_t)16 * 4);
    float* h0a   = (float*)alloc((size_t)RTOT * UU * 4);     // [b][u][n]
    float* h1a   = (float*)alloc((size_t)RTOT * UU * 4);
    float* xzero = (float*)alloc((size_t)RTOT * 4);
    float* h0b   = (float*)alloc((size_t)RTOT * UU * 4);
    float* h1b   = (float*)alloc((size_t)RTOT * UU * 4);
    float* g     = (float*)alloc((size_t)RTOT * 128 * 4);    // [b][u][n]: u<64 rh, u>=64 ugate
    float* p_e0g = (float*)alloc((size_t)5 * 64 * 128 * 4);
    float* x_e0g = (float*)alloc((size_t)16 * 5 * 8 * 4);
    float* p_e0c = (float*)alloc((size_t)5 * 64 * 64 * 4);
    float* x_e0c = (float*)alloc((size_t)16 * 5 * 4 * 4);
    float* p_e1g = (float*)alloc((size_t)5 * 128 * 128 * 4);
    float* p_e1c = (float*)alloc((size_t)5 * 128 * 64 * 4);
    float* p_d0g = (float*)alloc((size_t)5 * 64 * 128 * 4);
    float* x_d0g = (float*)alloc((size_t)16 * 5 * 8 * 4);
    float* p_d0c = (float*)alloc((size_t)5 * 64 * 64 * 4);
    float* x_d0c = (float*)alloc((size_t)16 * 5 * 4 * 4);
    float* p_d1g = (float*)alloc((size_t)5 * 128 * 128 * 4);
    float* p_d1c = (float*)alloc((size_t)5 * 128 * 64 * 4);
    float* xdum  = (float*)alloc((size_t)16 * 5 * 8 * 4);
    if (off > ws_size) return;

    // zero-fill ELL buffers (padding entries = {off 0, val 0}) BEFORE build
    {
        int nz = CAP * 1024 * 4;  // ell8 + ell4 as ints (contiguous)
        zero_kernel<<<(nz + 255) / 256, 256, 0, stream>>>((float*)ell8, nz);
    }
    build_ell<<<256, 256, 0, stream>>>(supports, ell8, ell4, ecnt);
    wmax_kernel<<<1, 16, 0, stream>>>(ecnt, wmax);
    {
        int nz = RTOT * UU * 2 + RTOT;  // h0a, h1a, xzero contiguous
        zero_kernel<<<(nz + 255) / 256, 256, 0, stream>>>(h0a, nz);
    }
    wprep<<<(5 * 64 * 128 + 255) / 256, 256, 0, stream>>>(enc0_Wg, p_e0g, x_e0g, 64, 128, 8, 1);
    wprep<<<(5 * 64 * 64 + 255) / 256, 256, 0, stream>>>(enc0_Wc, p_e0c, x_e0c, 64, 64, 4, 1);
    wprep<<<(5 * 128 * 128 + 255) / 256, 256, 0, stream>>>(enc1_Wg, p_e1g, xdum, 128, 128, 8, 0);
    wprep<<<(5 * 128 * 64 + 255) / 256, 256, 0, stream>>>(enc1_Wc, p_e1c, xdum, 128, 64, 4, 0);
    wprep<<<(5 * 64 * 128 + 255) / 256, 256, 0, stream>>>(dec0_Wg, p_d0g, x_d0g, 64, 128, 8, 1);
    wprep<<<(5 * 64 * 64 + 255) / 256, 256, 0, stream>>>(dec0_Wc, p_d0c, x_d0c, 64, 64, 4, 1);
    wprep<<<(5 * 128 * 128 + 255) / 256, 256, 0, stream>>>(dec1_Wg, p_d1g, xdum, 128, 128, 8, 0);
    wprep<<<(5 * 128 * 64 + 255) / 256, 256, 0, stream>>>(dec1_Wc, p_d1c, xdum, 128, 64, 4, 0);

    float *h0c = h0a, *h0n = h0b, *h1c = h1a, *h1n = h1b;

    auto cell_l0 = [&](const float* x_bn, const float* Wg_, const float* Xg_,
                       const float* bg_, const float* Wc_, const float* Xc_,
                       const float* bc_) {
        fused<true, true><<<512, 512, 0, stream>>>(h0c, nullptr, g, Wg_, Xg_, x_bn,
                                                   bg_, ell8, wmax, g, nullptr, nullptr);
        fused<true, false><<<512, 512, 0, stream>>>(h0c, nullptr, g, Wc_, Xc_, x_bn,
                                                    bc_, ell4, wmax, nullptr, h0c, h0n);
        float* t = h0c; h0c = h0n; h0n = t;
    };
    auto cell_l1 = [&](const float* Wg_, const float* bg_,
                       const float* Wc_, const float* bc_) {
        fused<false, true><<<512, 512, 0, stream>>>(h0c, h1c, g, Wg_, nullptr, nullptr,
                                                    bg_, ell8, wmax, g, nullptr, nullptr);
        fused<false, false><<<512, 512, 0, stream>>>(h0c, h1c, g, Wc_, nullptr, nullptr,
                                                     bc_, ell4, wmax, nullptr, h1c, h1n);
        float* t = h1c; h1c = h1n; h1n = t;
    };

    for (int t = 0; t < TT; ++t) {
        cell_l0(inputs + (size_t)t * BB * NN, p_e0g, x_e0g, enc0_bg, p_e0c, x_e0c, enc0_bc);
        cell_l1(p_e1g, enc1_bg, p_e1c, enc1_bc);
    }
    for (int t = 0; t < HH; ++t) {
        const float* xin = (t == 0) ? xzero : (out + (size_t)(t - 1) * BB * NN);
        cell_l0(xin, p_d0g, x_d0g, dec0_bg, p_d0c, x_d0c, dec0_bc);
        cell_l1(p_d1g, dec1_bg, p_d1c, dec1_bc);
        proj_kernel<<<(RTOT + 255) / 256, 256, 0, stream>>>(h1c, projW, projb,
                                                            out + (size_t)t * BB * NN);
    }
}

// Round 19
// 4651.991 us; speedup vs baseline: 1.1889x; 1.0251x over previous
//
#include <hip/hip_runtime.h>
#include <math.h>

#define NN 512
#define BB 32
#define TT 12
#define HH 12
#define UU 64
#define CAP 128
#define RTOT (NN * BB)          // 16384 rows

__device__ __forceinline__ float sigm(float x) { return 1.f / (1.f + expf(-x)); }

__global__ void zero_kernel(float* __restrict__ p, int n) {
    int i = blockIdx.x * 256 + threadIdx.x;
    if (i < n) p[i] = 0.0f;
}

// ---------------- per-row nonzero counts (wave per row, both supports) ----------
__global__ __launch_bounds__(256) void row_counts(const float* __restrict__ sup,
                                                  int* __restrict__ cnt) {
    int wave = (blockIdx.x * 256 + threadIdx.x) >> 6;
    int lane = threadIdx.x & 63;
    if (wave >= 2 * NN) return;
    const float* row = sup + (size_t)wave * NN;
    int c = 0;
    for (int k = 0; k < 8; ++k)
        c += __popcll(__ballot(row[k * 64 + lane] != 0.0f));
    if (lane == 0) cnt[wave] = c;
}

// ---------------- degree-sort permutation (deterministic counting sort) ---------
// key[n] = max(cnt0[n], cnt1[n]); ascending; ties broken by original index.
// nmap[new] = old, rankv[old] = new.
__global__ __launch_bounds__(512) void perm_build(const int* __restrict__ cnt,
                                                  int* __restrict__ nmap,
                                                  int* __restrict__ rankv) {
    __shared__ int hist[520];
    __shared__ int keys[512];
    int n = threadIdx.x;
    int c0 = cnt[n], c1 = cnt[NN + n];
    int key = c0 > c1 ? c0 : c1;          // <= 512
    hist[n] = 0;
    if (n < 8) hist[512 + n] = 0;
    __syncthreads();
    keys[n] = key;
    atomicAdd(&hist[key], 1);
    __syncthreads();
    if (n == 0) {
        int s = 0;
        for (int i = 0; i < 520; ++i) { int h = hist[i]; hist[i] = s; s += h; }
    }
    __syncthreads();
    int pos = hist[key];
    for (int i = 0; i < n; ++i)
        if (keys[i] == key) ++pos;        // deterministic tie-break by index
    nmap[pos] = n;
    rankv[n] = pos;
}

// ---------------- ELL build in permuted node space, pre-baked LDS offsets -------
// row r' (new) = nmap[r']; columns relabeled via rankv. Per-row entry ORDER is
// unchanged (original-j scan) -> per-row fp summation order identical.
// ell8: {j'*32 + ((j'>>2)&1)*16, val}; ell4: {j'*16, val}. Buffers pre-zeroed.
__global__ __launch_bounds__(256) void build_ell(const float* __restrict__ sup,
                                                 const int* __restrict__ nmap,
                                                 const int* __restrict__ rankv,
                                                 int2* __restrict__ ell8,
                                                 int2* __restrict__ ell4,
                                                 int* __restrict__ ecnt) {
    int wave = (blockIdx.x * blockDim.x + threadIdx.x) >> 6;
    int lane = threadIdx.x & 63;
    if (wave >= 2 * NN) return;
    int s = wave >> 9, rp = wave & 511;
    const float* row = sup + ((size_t)s * NN + nmap[rp]) * NN;
    int base = 0;
    for (int k = 0; k < NN / 64; ++k) {
        float v = row[k * 64 + lane];
        unsigned long long m = __ballot(v != 0.0f);
        int pre = __popcll(m & ((1ull << lane) - 1ull));
        if (v != 0.0f) {
            int pos = base + pre;
            if (pos < CAP) {
                int j = rankv[k * 64 + lane];
                int vb = __float_as_int(v);
                ell8[(size_t)pos * 1024 + wave] = make_int2(j * 32 + ((j >> 2) & 1) * 16, vb);
                ell4[(size_t)pos * 1024 + wave] = make_int2(j * 16, vb);
            }
        }
        base += __popcll(m);
    }
    if (lane == 0) ecnt[wave] = base < CAP ? base : CAP;
}

// per-64-row-group max counts: wmax[s*8+g] = max ecnt over rows [g*64, g*64+64)
__global__ void wmax_kernel(const int* __restrict__ ecnt, int* __restrict__ wmax) {
    int g = threadIdx.x;
    if (g >= 16) return;
    int s = g >> 3, grp = g & 7;
    int m = 0;
    for (int i = 0; i < 64; ++i) {
        int c = ecnt[s * NN + grp * 64 + i];
        m = c > m ? c : m;
    }
    wmax[g] = m;
}

// ---------------- weight prep: permute to [oq][m][c][WD] + x-row table ----------
// Wmod semantics: m=0 slot holds W0-W2-W4 (Chebyshev pre-subtraction).
__global__ void wprep(const float* __restrict__ src, float* __restrict__ dstP,
                      float* __restrict__ dstX, int C, int OO, int WD, int L0) {
    int idx = blockIdx.x * 256 + threadIdx.x;
    int total = 5 * C * OO;
    if (idx >= total) return;
    int oi = idx % WD;
    int rem = idx / WD;
    int c = rem % C;
    int rem2 = rem / C;
    int m = rem2 % 5;
    int oq = rem2 / 5;
    int o = oq * WD + oi;
    int crow = L0 ? (c + 1) : c;
    size_t base = (size_t)crow * 5 * OO + o;
    float v;
    if (m == 0) v = src[base] - src[base + 2 * OO] - src[base + 4 * OO];
    else        v = src[base + (size_t)m * OO];
    dstP[idx] = v;
    if (L0 && c == 0) {
        size_t b0 = (size_t)o;       // crow = 0
        float xvv;
        if (m == 0) xvv = src[b0] - src[b0 + 2 * OO] - src[b0 + 4 * OO];
        else        xvv = src[b0 + (size_t)m * OO];
        dstX[(oq * 5 + m) * WD + oi] = xvv;
    }
}

// ---------------- fused gconv: GEMM-in-registers + Chebyshev combine ------------
// All node-indexed state lives in PERMUTED space (lane n <-> original node
// nmap[n]); only xv loads and proj writes cross the boundary via nmap.
// Phase 1: acc[m][oi] = bias-init + sum_c A[c][n]*Wp[oq][m][c][oi]; W wave-uniform
// global (scalar cache). Phase 2: 2 LDS tiles, 4 gathers (pre-baked offsets,
// wave-uniform padded trip counts); out = Z024 + S1(Z1+2S1Z2) + S2(Z3+2S2Z4).
// GATE (WD=8): r-half -> g[u<64]=sigm(.)*h (rh-fusion); u-half -> g[u>=64]=sigm(.)
// CAND (WD=4): h_new = u*h_old + (1-u)*tanh(.); A loads rh directly from g.
template<bool L0, bool GATE>
__global__ __launch_bounds__(512) void fused(const float* __restrict__ hA,
                                             const float* __restrict__ hB,
                                             const float* __restrict__ g,
                                             const float* __restrict__ Wp,
                                             const float* __restrict__ Xr,
                                             const float* __restrict__ xv,
                                             const int* __restrict__ nmap,
                                             const float* __restrict__ bias,
                                             const int2* __restrict__ ell,
                                             const int* __restrict__ wmax,
                                             float* __restrict__ gout,
                                             const float* __restrict__ hOld,
                                             float* __restrict__ hNew) {
    constexpr int C  = L0 ? 64 : 128;
    constexpr int WD = GATE ? 8 : 4;

    __shared__ float S[512 * WD * 2];
    float* T0 = S;
    float* T1 = S + 512 * WD;

    int bid = blockIdx.x;
    int swz = (bid & 7) * 64 + (bid >> 3);  // XCD-contiguous (512 blocks, %8==0)
    int b = swz >> 4, oq = swz & 15;
    int o0 = oq * WD;
    int n = threadIdx.x;
    int wm0 = wmax[n >> 6];                 // wave-uniform trip counts
    int wm1 = wmax[8 + (n >> 6)];
    float xn = L0 ? xv[b * 512 + nmap[n]] : 0.f;

    // ---- phase 1: GEMM in registers; W via uniform global reads ----
    const float* Wb = Wp + (size_t)oq * 5 * C * WD;
    float acc[5][WD];
    #pragma unroll
    for (int oi = 0; oi < WD; ++oi) acc[0][oi] = bias[o0 + oi];   // bias-init
    #pragma unroll
    for (int m = 1; m < 5; ++m)
        #pragma unroll
        for (int oi = 0; oi < WD; ++oi) acc[m][oi] = 0.f;

    #pragma unroll 2
    for (int c = 0; c < C; ++c) {
        float a;
        if (L0) {
            if (GATE) a = hA[(size_t)((b << 6) + c) * 512 + n];
            else      a = g[(size_t)((b << 7) + c) * 512 + n];          // rh
        } else {
            if (c < 64) {
                a = hA[(size_t)((b << 6) + c) * 512 + n];
            } else {
                int u = c - 64;
                if (GATE) a = hB[(size_t)((b << 6) + u) * 512 + n];
                else      a = g[(size_t)((b << 7) + u) * 512 + n];      // rh
            }
        }
        #pragma unroll
        for (int m = 0; m < 5; ++m) {
            const float* wrow = Wb + ((size_t)m * C + c) * WD;
            #pragma unroll
            for (int oi = 0; oi < WD; ++oi)
                acc[m][oi] += a * wrow[oi];
        }
    }

    // rank-1 x-term (L0) from x-row table
    if (L0) {
        const float* xr = Xr + (size_t)oq * 5 * WD;
        #pragma unroll
        for (int m = 0; m < 5; ++m)
            #pragma unroll
            for (int oi = 0; oi < WD; ++oi)
                acc[m][oi] += xn * xr[m * WD + oi];
    }

    float uval[WD], hval[WD];
    if (!GATE) {
        #pragma unroll
        for (int oi = 0; oi < WD; ++oi) {
            uval[oi] = g[(size_t)((b << 7) + 64 + o0 + oi) * 512 + n];
            hval[oi] = hOld[(size_t)((b << 6) + o0 + oi) * 512 + n];
        }
    }

    // ---- stage Z2 -> T0, Z4 -> T1 (half-select by bit 2: matches ell8) ----
    int hsel = (n >> 2) & 1;
    if constexpr (WD == 8) {
        *(float4*)&T0[n * 8 + hsel * 4] =
            make_float4(acc[2][0], acc[2][1], acc[2][2], acc[2][3]);
        *(float4*)&T0[n * 8 + (hsel ^ 1) * 4] =
            make_float4(acc[2][4], acc[2][5], acc[2][6], acc[2][7]);
        *(float4*)&T1[n * 8 + hsel * 4] =
            make_float4(acc[4][0], acc[4][1], acc[4][2], acc[4][3]);
        *(float4*)&T1[n * 8 + (hsel ^ 1) * 4] =
            make_float4(acc[4][4], acc[4][5], acc[4][6], acc[4][7]);
    } else {
        *(float4*)&T0[n * 4] = make_float4(acc[2][0], acc[2][1], acc[2][2], acc[2][3]);
        *(float4*)&T1[n * 4] = make_float4(acc[4][0], acc[4][1], acc[4][2], acc[4][3]);
    }

    auto gather = [&](const float* T, const int2* e0, int wm, float* o) {
        const char* Tbyte = (const char*)T;
        float a0[WD];
        #pragma unroll
        for (int i = 0; i < WD; ++i) a0[i] = 0.f;
        #pragma unroll 2
        for (int p = 0; p < wm; ++p) {              // uniform, padded with zeros
            int2 e = e0[(size_t)p << 10];
            float v = __int_as_float(e.y);
            if constexpr (WD == 8) {
                float4 x0 = *(const float4*)(Tbyte + e.x);
                float4 x1 = *(const float4*)(Tbyte + (e.x ^ 16));
                a0[0] += v * x0.x; a0[1] += v * x0.y; a0[2] += v * x0.z; a0[3] += v * x0.w;
                a0[4] += v * x1.x; a0[5] += v * x1.y; a0[6] += v * x1.z; a0[7] += v * x1.w;
            } else {
                float4 x0 = *(const float4*)(Tbyte + e.x);
                a0[0] += v * x0.x; a0[1] += v * x0.y; a0[2] += v * x0.z; a0[3] += v * x0.w;
            }
        }
        #pragma unroll
        for (int i = 0; i < WD; ++i) o[i] = a0[i];
    };
    auto put = [&](float* T, const float* y) {
        if constexpr (WD == 8) {
            *(float4*)&T[n * 8 + hsel * 4]       = make_float4(y[0], y[1], y[2], y[3]);
            *(float4*)&T[n * 8 + (hsel ^ 1) * 4] = make_float4(y[4], y[5], y[6], y[7]);
        } else {
            *(float4*)&T[n * 4] = make_float4(y[0], y[1], y[2], y[3]);
        }
    };

    const int2* e00 = ell + n;          // support 0 row base
    const int2* e01 = ell + NN + n;     // support 1 row base
    float g2[WD], g4[WD], t1[WD];

    __syncthreads();                    // bar 1: T0/T1 staged

    gather(T0, e00, wm0, t1);           // S1 Z2
    #pragma unroll
    for (int oi = 0; oi < WD; ++oi) acc[1][oi] += 2.f * t1[oi];   // y1 = Z1+2 S1 Z2
    gather(T1, e01, wm1, t1);           // S2 Z4
    #pragma unroll
    for (int oi = 0; oi < WD; ++oi) acc[3][oi] += 2.f * t1[oi];   // y2 = Z3+2 S2 Z4

    __syncthreads();                    // bar 2: hop-1 reads done

    put(T0, acc[1]);
    put(T1, acc[3]);

    __syncthreads();                    // bar 3: y tiles ready

    gather(T0, e00, wm0, g2);           // S1 y1
    gather(T1, e01, wm1, g4);           // S2 y2

    #pragma unroll
    for (int oi = 0; oi < WD; ++oi) {
        float accf = acc[0][oi] + g2[oi] + g4[oi];
        if (GATE) {
            float s = sigm(accf);
            if (oq < 8) {               // r-half: write rh = r * h (rh-fusion)
                const float* hG = L0 ? hA : hB;
                float hv = hG[(size_t)((b << 6) + o0 + oi) * 512 + n];
                gout[(size_t)((b << 7) + o0 + oi) * 512 + n] = s * hv;
            } else {
                gout[(size_t)((b << 7) + o0 + oi) * 512 + n] = s;
            }
        } else {
            float cv = tanhf(accf);
            hNew[(size_t)((b << 6) + o0 + oi) * 512 + n] =
                uval[oi] * hval[oi] + (1.f - uval[oi]) * cv;
        }
    }
}

// ---------------- projection (write through nmap to original node order) --------
__global__ void proj_kernel(const float* __restrict__ h1, const float* __restrict__ pW,
                            const float* __restrict__ pb, const int* __restrict__ nmap,
                            float* __restrict__ outt) {
    int r = blockIdx.x * 256 + threadIdx.x;
    if (r >= RTOT) return;
    int b = r >> 9, n = r & 511;
    float acc = pb[0];
    #pragma unroll 16
    for (int u = 0; u < 64; ++u)
        acc += h1[(size_t)((b << 6) + u) * 512 + n] * pW[u];
    outt[b * NN + nmap[n]] = acc;
}

// ================================================================================
extern "C" void kernel_launch(void* const* d_in, const int* in_sizes, int n_in,
                              void* d_out, int out_size, void* d_ws, size_t ws_size,
                              hipStream_t stream) {
    const float* inputs   = (const float*)d_in[0];
    const float* supports = (const float*)d_in[1];
    const float* enc0_Wg = (const float*)d_in[2];
    const float* enc0_bg = (const float*)d_in[3];
    const float* enc0_Wc = (const float*)d_in[4];
    const float* enc0_bc = (const float*)d_in[5];
    const float* enc1_Wg = (const float*)d_in[6];
    const float* enc1_bg = (const float*)d_in[7];
    const float* enc1_Wc = (const float*)d_in[8];
    const float* enc1_bc = (const float*)d_in[9];
    const float* dec0_Wg = (const float*)d_in[10];
    const float* dec0_bg = (const float*)d_in[11];
    const float* dec0_Wc = (const float*)d_in[12];
    const float* dec0_bc = (const float*)d_in[13];
    const float* dec1_Wg = (const float*)d_in[14];
    const float* dec1_bg = (const float*)d_in[15];
    const float* dec1_Wc = (const float*)d_in[16];
    const float* dec1_bc = (const float*)d_in[17];
    const float* projW   = (const float*)d_in[18];
    const float* projb   = (const float*)d_in[19];
    float* out = (float*)d_out;

    char* wsb = (char*)d_ws;
    size_t off = 0;
    auto alloc = [&](size_t bytes) -> char* {
        char* p = wsb + off;
        off = (off + bytes + 255) & ~(size_t)255;
        return p;
    };
    int2*  ell8  = (int2*)alloc((size_t)CAP * 1024 * 8);
    int2*  ell4  = (int2*)alloc((size_t)CAP * 1024 * 8);
    int*   cnt   = (int*)alloc((size_t)2 * NN * 4);
    int*   nmap  = (int*)alloc((size_t)NN * 4);
    int*   rankv = (int*)alloc((size_t)NN * 4);
    int*   ecnt  = (int*)alloc((size_t)2 * NN * 4);
    int*   wmax  = (int*)alloc((size_t)16 * 4);
    float* h0a   = (float*)alloc((size_t)RTOT * UU * 4);     // [b][u][n]
    float* h1a   = (float*)alloc((size_t)RTOT * UU * 4);
    float* xzero = (float*)alloc((size_t)RTOT * 4);
    float* h0b   = (float*)alloc((size_t)RTOT * UU * 4);
    float* h1b   = (float*)alloc((size_t)RTOT * UU * 4);
    float* g     = (float*)alloc((size_t)RTOT * 128 * 4);    // [b][u][n]: u<64 rh, u>=64 ugate
    float* p_e0g = (float*)alloc((size_t)5 * 64 * 128 * 4);
    float* x_e0g = (float*)alloc((size_t)16 * 5 * 8 * 4);
    float* p_e0c = (float*)alloc((size_t)5 * 64 * 64 * 4);
    float* x_e0c = (float*)alloc((size_t)16 * 5 * 4 * 4);
    float* p_e1g = (float*)alloc((size_t)5 * 128 * 128 * 4);
    float* p_e1c = (float*)alloc((size_t)5 * 128 * 64 * 4);
    float* p_d0g = (float*)alloc((size_t)5 * 64 * 128 * 4);
    float* x_d0g = (float*)alloc((size_t)16 * 5 * 8 * 4);
    float* p_d0c = (float*)alloc((size_t)5 * 64 * 64 * 4);
    float* x_d0c = (float*)alloc((size_t)16 * 5 * 4 * 4);
    float* p_d1g = (float*)alloc((size_t)5 * 128 * 128 * 4);
    float* p_d1c = (float*)alloc((size_t)5 * 128 * 64 * 4);
    float* xdum  = (float*)alloc((size_t)16 * 5 * 8 * 4);
    if (off > ws_size) return;

    // permutation + ELL (zero-fill first: padding entries = {off 0, val 0})
    {
        int nz = CAP * 1024 * 4;  // ell8 + ell4 as ints (contiguous)
        zero_kernel<<<(nz + 255) / 256, 256, 0, stream>>>((float*)ell8, nz);
    }
    row_counts<<<256, 256, 0, stream>>>(supports, cnt);
    perm_build<<<1, 512, 0, stream>>>(cnt, nmap, rankv);
    build_ell<<<256, 256, 0, stream>>>(supports, nmap, rankv, ell8, ell4, ecnt);
    wmax_kernel<<<1, 16, 0, stream>>>(ecnt, wmax);
    {
        int nz = RTOT * UU * 2 + RTOT;  // h0a, h1a, xzero contiguous
        zero_kernel<<<(nz + 255) / 256, 256, 0, stream>>>(h0a, nz);
    }
    wprep<<<(5 * 64 * 128 + 255) / 256, 256, 0, stream>>>(enc0_Wg, p_e0g, x_e0g, 64, 128, 8, 1);
    wprep<<<(5 * 64 * 64 + 255) / 256, 256, 0, stream>>>(enc0_Wc, p_e0c, x_e0c, 64, 64, 4, 1);
    wprep<<<(5 * 128 * 128 + 255) / 256, 256, 0, stream>>>(enc1_Wg, p_e1g, xdum, 128, 128, 8, 0);
    wprep<<<(5 * 128 * 64 + 255) / 256, 256, 0, stream>>>(enc1_Wc, p_e1c, xdum, 128, 64, 4, 0);
    wprep<<<(5 * 64 * 128 + 255) / 256, 256, 0, stream>>>(dec0_Wg, p_d0g, x_d0g, 64, 128, 8, 1);
    wprep<<<(5 * 64 * 64 + 255) / 256, 256, 0, stream>>>(dec0_Wc, p_d0c, x_d0c, 64, 64, 4, 1);
    wprep<<<(5 * 128 * 128 + 255) / 256, 256, 0, stream>>>(dec1_Wg, p_d1g, xdum, 128, 128, 8, 0);
    wprep<<<(5 * 128 * 64 + 255) / 256, 256, 0, stream>>>(dec1_Wc, p_d1c, xdum, 128, 64, 4, 0);

    float *h0c = h0a, *h0n = h0b, *h1c = h1a, *h1n = h1b;

    auto cell_l0 = [&](const float* x_bn, const float* Wg_, const float* Xg_,
                       const float* bg_, const float* Wc_, const float* Xc_,
                       const float* bc_) {
        fused<true, true><<<512, 512, 0, stream>>>(h0c, nullptr, g, Wg_, Xg_, x_bn, nmap,
                                                   bg_, ell8, wmax, g, nullptr, nullptr);
        fused<true, false><<<512, 512, 0, stream>>>(h0c, nullptr, g, Wc_, Xc_, x_bn, nmap,
                                                    bc_, ell4, wmax, nullptr, h0c, h0n);
        float* t = h0c; h0c = h0n; h0n = t;
    };
    auto cell_l1 = [&](const float* Wg_, const float* bg_,
                       const float* Wc_, const float* bc_) {
        fused<false, true><<<512, 512, 0, stream>>>(h0c, h1c, g, Wg_, nullptr, nullptr, nmap,
                                                    bg_, ell8, wmax, g, nullptr, nullptr);
        fused<false, false><<<512, 512, 0, stream>>>(h0c, h1c, g, Wc_, nullptr, nullptr, nmap,
                                                     bc_, ell4, wmax, nullptr, h1c, h1n);
        float* t = h1c; h1c = h1n; h1n = t;
    };

    for (int t = 0; t < TT; ++t) {
        cell_l0(inputs + (size_t)t * BB * NN, p_e0g, x_e0g, enc0_bg, p_e0c, x_e0c, enc0_bc);
        cell_l1(p_e1g, enc1_bg, p_e1c, enc1_bc);
    }
    for (int t = 0; t < HH; ++t) {
        const float* xin = (t == 0) ? xzero : (out + (size_t)(t - 1) * BB * NN);
        cell_l0(xin, p_d0g, x_d0g, dec0_bg, p_d0c, x_d0c, dec0_bc);
        cell_l1(p_d1g, dec1_bg, p_d1c, dec1_bc);
        proj_kernel<<<(RTOT + 255) / 256, 256, 0, stream>>>(h1c, projW, projb, nmap,
                                                            out + (size_t)t * BB * NN);
    }
}